// Round 6
// baseline (297.502 us; speedup 1.0000x reference)
//
#include <hip/hip_runtime.h>
#include <hip/hip_bf16.h>

// ---------------------------------------------------------------------------
// Graph transformer layer, fp32 in/out; bf16 MFMA GEMMs; f16 q/k dot via
// v_dot2_f32_f16; f16 v gather with f32 mixed-FMA accumulate (v_fma_mix_f32).
// Pipeline:
//   1. bucket partition (128 rows/bucket, edge dtype detected per-block)
//      -> packed records -> per-bucket counting sort -> CSR
//   2. cvt_w: weights -> bf16 W^T (QKV converts fp32 A fragments inline;
//      attn residual reads fp32 x directly)
//   3. QKV via MFMA: q (pre-scaled log2e/8) -> f16 qbuf[N][64];
//      kv[N][256B]: k f16 [0,128) (h*16) then v f16 [128,256) (h*16)
//   4. attn+LN1 fused: one wave per TWO nodes, lane = e*16 + p*8 + h.
//   5. FFN1 relu via MFMA -> bf16 h ; FFN2 via MFMA + bf16 residual + LN2
// GEMM shape: 64 rows/block, 4 waves x 16 rows (acc regs halved vs 128-row
// blocks -> 4 waves/SIMD occupancy for the streaming A/out traffic).
// MFMA operand swap: arg0 = W^T frag (LDS), arg1 = X frag (global) so lane
// owns an output row, 4 consecutive cols per acc reg -> vector stores,
// row-LN via shfl_xor(16,32).
// ---------------------------------------------------------------------------

#define WAVE 64
constexpr int BUCKET_SHIFT = 7;
constexpr int NBMAX = 800;
constexpr int NBLK = 1024;  // partition grid

typedef __attribute__((ext_vector_type(8))) short bf16x8;
typedef __attribute__((ext_vector_type(4))) float f32x4;
typedef __attribute__((ext_vector_type(2))) float f32x2;
typedef __attribute__((ext_vector_type(2))) _Float16 h16x2;

__device__ __forceinline__ float bfbits_lo(unsigned u) {
  return __uint_as_float(u << 16);
}
__device__ __forceinline__ float bfbits_hi(unsigned u) {
  return __uint_as_float(u & 0xffff0000u);
}
__device__ __forceinline__ unsigned f2bf_pk(float a, float b) {  // RNE pack
  unsigned ua = __float_as_uint(a);
  unsigned ub = __float_as_uint(b);
  ua = (ua + 0x7fff + ((ua >> 16) & 1)) >> 16;
  ub = (ub + 0x7fff + ((ub >> 16) & 1)) & 0xffff0000u;
  return ua | ub;
}
__device__ __forceinline__ unsigned short f2bf1(float a) {
  unsigned ua = __float_as_uint(a);
  ua = (ua + 0x7fff + ((ua >> 16) & 1)) >> 16;
  return (unsigned short)ua;
}

#if defined(__has_builtin)
#if __has_builtin(__builtin_amdgcn_cvt_pkrtz)
#define HAS_PKRTZ 1
#endif
#if __has_builtin(__builtin_amdgcn_fdot2)
#define HAS_FDOT2 1
#endif
#endif
#define EXP2F(x) exp2f(x)

__device__ __forceinline__ unsigned f2h_pk(float a, float b) {
#ifdef HAS_PKRTZ
  auto h = __builtin_amdgcn_cvt_pkrtz(a, b);  // __fp16 ext_vector(2)
  return __builtin_bit_cast(unsigned, h);
#else
  h16x2 h;
  h.x = (_Float16)a;
  h.y = (_Float16)b;
  return __builtin_bit_cast(unsigned, h);
#endif
}

// 8-wide f16 dot: k row (4x half2) vs q row (4x half2), f32 accumulate
__device__ __forceinline__ float dot8_f16(uint4 kw, uint4 qw) {
#ifdef HAS_FDOT2
  float s = __builtin_amdgcn_fdot2(__builtin_bit_cast(h16x2, kw.x),
                                   __builtin_bit_cast(h16x2, qw.x), 0.f, false);
  s = __builtin_amdgcn_fdot2(__builtin_bit_cast(h16x2, kw.y),
                             __builtin_bit_cast(h16x2, qw.y), s, false);
  s = __builtin_amdgcn_fdot2(__builtin_bit_cast(h16x2, kw.z),
                             __builtin_bit_cast(h16x2, qw.z), s, false);
  s = __builtin_amdgcn_fdot2(__builtin_bit_cast(h16x2, kw.w),
                             __builtin_bit_cast(h16x2, qw.w), s, false);
  return s;
#else
  unsigned kk[4] = {kw.x, kw.y, kw.z, kw.w};
  unsigned qq[4] = {qw.x, qw.y, qw.z, qw.w};
  float s = 0.f;
#pragma unroll
  for (int i = 0; i < 4; i++) {
    h16x2 a = __builtin_bit_cast(h16x2, kk[i]);
    h16x2 b = __builtin_bit_cast(h16x2, qq[i]);
    s += (float)a.x * (float)b.x + (float)a.y * (float)b.y;
  }
  return s;
#endif
}

// 8 f16 v-elems (uint4) * e -> f32 accumulate; pattern-matches v_fma_mix_f32
__device__ __forceinline__ void accmix8(uint4 w, float e, float acc[8]) {
  h16x2 p;
  p = __builtin_bit_cast(h16x2, w.x);
  acc[0] += (float)p.x * e;
  acc[1] += (float)p.y * e;
  p = __builtin_bit_cast(h16x2, w.y);
  acc[2] += (float)p.x * e;
  acc[3] += (float)p.y * e;
  p = __builtin_bit_cast(h16x2, w.z);
  acc[4] += (float)p.x * e;
  acc[5] += (float)p.y * e;
  p = __builtin_bit_cast(h16x2, w.w);
  acc[6] += (float)p.x * e;
  acc[7] += (float)p.y * e;
}

// ------------------------- weight converts ---------------------------------
__global__ __launch_bounds__(256) void cvt_w2(
    const float* __restrict__ aw, const float* __restrict__ w1,
    const float* __restrict__ w2, unsigned short* __restrict__ awT,
    unsigned short* __restrict__ w1T, unsigned short* __restrict__ w2T) {
  int tid = blockIdx.x * 256 + threadIdx.x;
  int stride = gridDim.x * 256;
  for (int i = tid; i < 192 * 64; i += stride) {
    int nn = i >> 6, kk = i & 63;
    awT[i] = f2bf1(aw[kk * 192 + nn]);
  }
  for (int i = tid; i < 256 * 64; i += stride) {
    int nn = i >> 6, kk = i & 63;
    w1T[i] = f2bf1(w1[kk * 256 + nn]);
  }
  for (int i = tid; i < 64 * 256; i += stride) {
    int nn = i >> 8, kk = i & 255;
    w2T[i] = f2bf1(w2[kk * 64 + nn]);
  }
}

// ------------------------- MFMA GEMM ---------------------------------------
// 64 rows/block, 4 waves x 16 rows.
// MODE 0: QKV split, A is fp32 (converted inline):
//         q*(log2e/8) -> f16 out_q[N][64]; k -> f16 kv[0,128); v -> f16 [128,256)
// MODE 1: relu + bf16 store -> out_h
// MODE 2: + bias + bf16 resid, LayerNorm over 64 cols -> out_f fp32
template <int NCOLS, int K, int MODE>
__global__ __launch_bounds__(256) void mfma_gemm(
    const unsigned short* __restrict__ A, const float* __restrict__ Af,
    const unsigned short* __restrict__ BT, const float* __restrict__ bias,
    unsigned short* __restrict__ out_q, unsigned char* __restrict__ out_kv,
    unsigned short* __restrict__ out_h,
    const unsigned short* __restrict__ resid, const float* __restrict__ g,
    const float* __restrict__ beta, float* __restrict__ out_f, int n) {
  constexpr int KP = K + 8;  // +16B pad -> only free 2-way bank alias
  constexpr int NT = NCOLS / 16;
  constexpr int NKC = K / 32;
  __shared__ unsigned short sB[NCOLS * KP];

  const int tid = threadIdx.x;
  {
    const uint4* src = (const uint4*)BT;
    for (int idx = tid; idx < NCOLS * K / 8; idx += 256) {
      int nn = idx / (K / 8), kq = idx % (K / 8);
      *(uint4*)&sB[nn * KP + kq * 8] = src[idx];
    }
  }
  __syncthreads();

  const int wid = tid >> 6, lane = tid & 63;
  const int l15 = lane & 15, quad = lane >> 4;
  const int row0 = blockIdx.x * 64 + wid * 16 + l15;
  const int row = (row0 < n) ? row0 : (n - 1);

  bf16x8 afrag[NKC];
  if constexpr (MODE == 0) {
    const float4* ap = (const float4*)(Af + (size_t)row * K);
#pragma unroll
    for (int kc = 0; kc < NKC; kc++) {
      float4 a = ap[kc * 8 + quad * 2], b = ap[kc * 8 + quad * 2 + 1];
      union {
        unsigned u[4];
        bf16x8 v;
      } z;
      z.u[0] = f2bf_pk(a.x, a.y);
      z.u[1] = f2bf_pk(a.z, a.w);
      z.u[2] = f2bf_pk(b.x, b.y);
      z.u[3] = f2bf_pk(b.z, b.w);
      afrag[kc] = z.v;
    }
  } else {
    const bf16x8* ap = (const bf16x8*)(A + (size_t)row * K);
#pragma unroll
    for (int kc = 0; kc < NKC; kc++) afrag[kc] = ap[kc * 4 + quad];
  }

  f32x4 acc[NT];
#pragma unroll
  for (int t = 0; t < NT; t++) acc[t] = (f32x4){0.f, 0.f, 0.f, 0.f};

#pragma unroll
  for (int t = 0; t < NT; t++) {
#pragma unroll
    for (int kc = 0; kc < NKC; kc++) {
      bf16x8 b = *(const bf16x8*)&sB[(t * 16 + l15) * KP + kc * 32 + quad * 8];
      acc[t] =
          __builtin_amdgcn_mfma_f32_16x16x32_bf16(b, afrag[kc], acc[t], 0, 0, 0);
    }
  }

  if (MODE == 0) {
    constexpr float QSCALE = 0.125f * 1.44269504088896f;  // log2e/8
    if (row0 < n) {
#pragma unroll
      for (int t = 0; t < NT; t++) {
        int c0 = t * 16 + quad * 4;
        float4 bb = *(const float4*)&bias[c0];
        float v0 = acc[t].x + bb.x, v1 = acc[t].y + bb.y;
        float v2 = acc[t].z + bb.z, v3 = acc[t].w + bb.w;
        int hh = c0 / 24, rem = c0 % 24;  // 4-col group stays in one section
        if (rem < 8) {
          v0 *= QSCALE;
          v1 *= QSCALE;
          v2 *= QSCALE;
          v3 *= QSCALE;
          *(uint2*)(out_q + (size_t)row * 64 + hh * 8 + rem) =
              make_uint2(f2h_pk(v0, v1), f2h_pk(v2, v3));  // q f16 (log2 dom)
        } else if (rem < 16) {
          *(uint2*)(out_kv + ((size_t)row << 8) + hh * 16 + (rem - 8) * 2) =
              make_uint2(f2h_pk(v0, v1), f2h_pk(v2, v3));  // k f16 [0,128)
        } else {
          *(uint2*)(out_kv + ((size_t)row << 8) + 128 + hh * 16 +
                    (rem - 16) * 2) =
              make_uint2(f2h_pk(v0, v1), f2h_pk(v2, v3));  // v f16 [128,256)
        }
      }
    }
  } else if (MODE == 1) {
    if (row0 < n) {
#pragma unroll
      for (int t = 0; t < NT; t++) {
        int c0 = t * 16 + quad * 4;
        float4 bb = *(const float4*)&bias[c0];
        float v0 = fmaxf(acc[t].x + bb.x, 0.f);
        float v1 = fmaxf(acc[t].y + bb.y, 0.f);
        float v2 = fmaxf(acc[t].z + bb.z, 0.f);
        float v3 = fmaxf(acc[t].w + bb.w, 0.f);
        *(uint2*)(out_h + (size_t)row * NCOLS + c0) =
            make_uint2(f2bf_pk(v0, v1), f2bf_pk(v2, v3));
      }
    }
  } else {
    bool ok = row0 < n;
    float vals[4][4];
    float ps = 0.f, pq = 0.f;
#pragma unroll
    for (int t = 0; t < 4; t++) {
      int c0 = t * 16 + quad * 4;
      float4 bb = *(const float4*)&bias[c0];
      uint2 rr = *(const uint2*)&resid[(size_t)row * 64 + c0];
      vals[t][0] = acc[t].x + bb.x + bfbits_lo(rr.x);
      vals[t][1] = acc[t].y + bb.y + bfbits_hi(rr.x);
      vals[t][2] = acc[t].z + bb.z + bfbits_lo(rr.y);
      vals[t][3] = acc[t].w + bb.w + bfbits_hi(rr.y);
#pragma unroll
      for (int r = 0; r < 4; r++) {
        ps += vals[t][r];
        pq += vals[t][r] * vals[t][r];
      }
    }
    ps += __shfl_xor(ps, 16);
    ps += __shfl_xor(ps, 32);
    pq += __shfl_xor(pq, 16);
    pq += __shfl_xor(pq, 32);
    float mean = ps * (1.f / 64.f);
    float var = pq * (1.f / 64.f) - mean * mean;
    float inv = rsqrtf(var + 1e-5f);
    if (ok) {
#pragma unroll
      for (int t = 0; t < 4; t++) {
        int c0 = t * 16 + quad * 4;
        float4 gg = *(const float4*)&g[c0];
        float4 be = *(const float4*)&beta[c0];
        float4 o = make_float4((vals[t][0] - mean) * inv * gg.x + be.x,
                               (vals[t][1] - mean) * inv * gg.y + be.y,
                               (vals[t][2] - mean) * inv * gg.z + be.z,
                               (vals[t][3] - mean) * inv * gg.w + be.w);
        *(float4*)&out_f[(size_t)row * 64 + c0] = o;
      }
    }
  }
}

// ------------------------- edge helpers ------------------------------------
__device__ __forceinline__ int edge_row(const int* e, int i, bool is64) {
  return is64 ? ((const int2*)e)[i].x : e[i];
}
__device__ __forceinline__ int edge_col(const int* e, int i, int E, bool is64) {
  return is64 ? ((const int2*)e)[(size_t)E + i].x : e[(size_t)E + i];
}

// ------------------------- bucket partition --------------------------------
// Edge dtype (int64 vs int32) detected per-block: sample the first 2048
// odd-index words; int64 high words are all 0, int32 edge data is not.
__global__ __launch_bounds__(256) void partition_count(
    const int* __restrict__ e, int E, int* __restrict__ G, int NB, int CH) {
  __shared__ int h[NBMAX];
  __shared__ int s32;
  if (threadIdx.x == 0) s32 = 0;
  for (int b = threadIdx.x; b < NB; b += 256) h[b] = 0;
  __syncthreads();
  unsigned v = 0;
  for (int i = threadIdx.x; i < 2048; i += 256) v |= (unsigned)e[2 * i + 1];
  if (v) s32 = 1;
  __syncthreads();
  bool is64 = (s32 == 0);
  int c0 = blockIdx.x * CH, c1 = min(E, c0 + CH);
  for (int i = c0 + threadIdx.x; i < c1; i += 256)
    atomicAdd(&h[edge_row(e, i, is64) >> BUCKET_SHIFT], 1);
  __syncthreads();
  for (int b = threadIdx.x; b < NB; b += 256) G[b * NBLK + blockIdx.x] = h[b];
}

__global__ __launch_bounds__(1024) void scan_reduce(const int* __restrict__ in,
                                                    int n,
                                                    int* __restrict__ bsum) {
  __shared__ int sdata[16];
  int tid = threadIdx.x;
  int idx = blockIdx.x * 1024 + tid;
  int v = (idx < n) ? in[idx] : 0;
#pragma unroll
  for (int m = 1; m < WAVE; m <<= 1) v += __shfl_xor(v, m);
  if ((tid & 63) == 0) sdata[tid >> 6] = v;
  __syncthreads();
  if (tid < 16) {
    int s = sdata[tid];
#pragma unroll
    for (int m = 1; m < 16; m <<= 1) s += __shfl_xor(s, m);
    if (tid == 0) bsum[blockIdx.x] = s;
  }
}

// exclusive scan of bsum[0..nb) -> bpre, chunked 1024 with running carry
__global__ __launch_bounds__(1024) void scan_top(const int* __restrict__ bsum,
                                                 int nb,
                                                 int* __restrict__ bpre) {
  __shared__ int wsum[16];
  __shared__ int carry;
  int tid = threadIdx.x, lane = tid & 63, wid = tid >> 6;
  if (tid == 0) carry = 0;
  __syncthreads();
  for (int base = 0; base < nb; base += 1024) {
    int idx = base + tid;
    int v = (idx < nb) ? bsum[idx] : 0;
    int incl = v;
#pragma unroll
    for (int m = 1; m < WAVE; m <<= 1) {
      int t = __shfl_up(incl, m);
      if (lane >= m) incl += t;
    }
    if (lane == 63) wsum[wid] = incl;
    __syncthreads();
    int add = carry;
    for (int w = 0; w < wid; w++) add += wsum[w];
    if (idx < nb) bpre[idx] = add + incl - v;
    __syncthreads();
    if (tid == 0) {
      int t = 0;
      for (int w = 0; w < 16; w++) t += wsum[w];
      carry += t;
    }
    __syncthreads();
  }
}

__global__ __launch_bounds__(1024) void scan_apply(
    const int* __restrict__ in, int n, const int* __restrict__ bpre,
    int* __restrict__ outscan) {
  __shared__ int wtot[16];
  __shared__ int wexcl[16];
  int tid = threadIdx.x;
  int idx = blockIdx.x * 1024 + tid;
  int v = (idx < n) ? in[idx] : 0;
  int incl = v;
#pragma unroll
  for (int m = 1; m < WAVE; m <<= 1) {
    int t = __shfl_up(incl, m);
    if ((tid & 63) >= m) incl += t;
  }
  int wid = tid >> 6;
  if ((tid & 63) == 63) wtot[wid] = incl;
  __syncthreads();
  if (tid < 16) {
    int w = wtot[tid];
    int wi = w;
#pragma unroll
    for (int m = 1; m < 16; m <<= 1) {
      int t = __shfl_up(wi, m);
      if (tid >= m) wi += t;
    }
    wexcl[tid] = wi - w;
  }
  __syncthreads();
  if (idx < n) outscan[idx] = bpre[blockIdx.x] + wexcl[wid] + incl - v;
}

__global__ __launch_bounds__(256) void partition_scatter(
    const int* __restrict__ e, int E, const int* __restrict__ scanG,
    unsigned* __restrict__ ebuf, int NB, int CH) {
  __shared__ int base[NBMAX];
  __shared__ int s32;
  if (threadIdx.x == 0) s32 = 0;
  for (int b = threadIdx.x; b < NB; b += 256)
    base[b] = scanG[b * NBLK + blockIdx.x];
  __syncthreads();
  unsigned v = 0;
  for (int i = threadIdx.x; i < 2048; i += 256) v |= (unsigned)e[2 * i + 1];
  if (v) s32 = 1;
  __syncthreads();
  bool is64 = (s32 == 0);
  int c0 = blockIdx.x * CH, c1 = min(E, c0 + CH);
  for (int i = c0 + threadIdx.x; i < c1; i += 256) {
    int r = edge_row(e, i, is64);
    int c = edge_col(e, i, E, is64);
    int pos = atomicAdd(&base[r >> BUCKET_SHIFT], 1);
    ebuf[pos] = ((unsigned)(r & 127) << 17) | (unsigned)c;
  }
}

__global__ __launch_bounds__(256) void bucket_csr(
    const unsigned* __restrict__ ebuf, const int* __restrict__ scanG,
    int* __restrict__ ecol, int* __restrict__ rowstart, int n, int NB, int E) {
  __shared__ int cnt[128], offs[128], cur[128];
  const int b = blockIdx.x;
  const int tid = threadIdx.x;
  const int start = scanG[b * NBLK];
  const int end = (b + 1 < NB) ? scanG[(b + 1) * NBLK] : E;
  if (tid < 128) cnt[tid] = 0;
  __syncthreads();
  for (int i = start + tid; i < end; i += 256)
    atomicAdd(&cnt[(ebuf[i] >> 17) & 127], 1);
  __syncthreads();
  if (tid < 128) offs[tid] = cnt[tid];
  __syncthreads();
  for (int s = 1; s < 128; s <<= 1) {
    int t = 0;
    if (tid < 128 && tid >= s) t = offs[tid - s];
    __syncthreads();
    if (tid < 128) offs[tid] += t;
    __syncthreads();
  }
  if (tid < 128) {
    int excl = offs[tid] - cnt[tid];
    cur[tid] = start + excl;
    int gr = (b << BUCKET_SHIFT) + tid;
    if (gr < n) rowstart[gr] = start + excl;
  }
  if (b == NB - 1 && tid == 0) rowstart[n] = E;
  __syncthreads();
  for (int i = start + tid; i < end; i += 256) {
    unsigned p = ebuf[i];
    int pos = atomicAdd(&cur[(p >> 17) & 127], 1);
    ecol[pos] = (int)(p & 0x1FFFF);
  }
}

// ------------------------- fused attention + LN1 ---------------------------
// One wave per TWO nodes; lane = e*16 + p*8 + h (e=edge-slot 0..3, p=node
// parity, h=head). kv per node (256B): [0,128) k f16 (h*16), [128,256) v f16.
// q pre-scaled by log2e/8 (f16, log2 domain). Residual from fp32 x.
// e-reduce = shfl_xor 16,32 (2 levels); h-reduce for LN = shfl_xor 1,2,4.
__global__ __launch_bounds__(256) void attn_ln_kernel(
    const float* __restrict__ x, const unsigned short* __restrict__ qbuf,
    const unsigned char* __restrict__ kv, const int* __restrict__ rowstart,
    const int* __restrict__ ecol, const float* __restrict__ g,
    const float* __restrict__ beta, unsigned short* __restrict__ x1b, int n) {
  int wave = threadIdx.x >> 6;
  int lane = threadIdx.x & 63;
  int node0 = (blockIdx.x * 4 + wave) * 2;
  if (node0 >= n) return;
  const int e = lane >> 4;  // 0..3 edge slot
  const int h = lane & 7;   // head
  int node = node0 + ((lane >> 3) & 1);
  bool nvalid = node < n;
  int nodec = nvalid ? node : n - 1;

  uint4 qp = ((const uint4*)qbuf)[(size_t)nodec * 8 + h];  // 8 f16, log2 dom

  // residual load hoisted above the edge loop
  const float* xr = x + (size_t)nodec * 64 + h * 8;
  float4 x0 = *(const float4*)xr;
  float4 x1 = *(const float4*)(xr + 4);

  int start = rowstart[nodec];
  int cnt = nvalid ? rowstart[nodec + 1] - start : 0;
  const int* ec = ecol + start;
  const int koff = h * 16, voff = 128 + h * 16;

  float den = 0.f;
  float acc[8] = {0.f, 0.f, 0.f, 0.f, 0.f, 0.f, 0.f, 0.f};

  int iters = (cnt + 3) >> 2;
  int maxit = max(iters, __shfl_xor(iters, 8));  // pair with p^1 lane

  int it = 0;
  for (; it + 2 <= maxit; it += 2) {
    int i0 = it * 4 + e;
    int i1 = i0 + 4;
    bool b0 = i0 < cnt;
    bool b1 = i1 < cnt;
    int c0 = ec[b0 ? i0 : 0] & 0x1FFFF;  // mask keeps OOB reads in workspace
    int c1 = ec[b1 ? i1 : 0] & 0x1FFFF;
    const unsigned char* r0 = kv + ((size_t)c0 << 8);
    const unsigned char* r1 = kv + ((size_t)c1 << 8);
    uint4 kw0 = *(const uint4*)(r0 + koff);
    uint4 vw0 = *(const uint4*)(r0 + voff);
    uint4 kw1 = *(const uint4*)(r1 + koff);
    uint4 vw1 = *(const uint4*)(r1 + voff);
    float a0 = dot8_f16(kw0, qp);
    float a1 = dot8_f16(kw1, qp);
    float e0 = b0 ? EXP2F(a0) : 0.f;
    float e1 = b1 ? EXP2F(a1) : 0.f;
    den += e0 + e1;
    accmix8(vw0, e0, acc);
    accmix8(vw1, e1, acc);
  }
  if (it < maxit) {
    int i0 = it * 4 + e;
    bool b0 = i0 < cnt;
    int c0 = ec[b0 ? i0 : 0] & 0x1FFFF;
    const unsigned char* r0 = kv + ((size_t)c0 << 8);
    uint4 kw0 = *(const uint4*)(r0 + koff);
    uint4 vw0 = *(const uint4*)(r0 + voff);
    float a0 = dot8_f16(kw0, qp);
    float e0 = b0 ? EXP2F(a0) : 0.f;
    den += e0;
    accmix8(vw0, e0, acc);
  }

  // reduce over the 4 edge-slots (flip e bits: 16, 32); p and h preserved
#pragma unroll
  for (int m = 16; m < 64; m <<= 1) {
    den += __shfl_xor(den, m);
#pragma unroll
    for (int j = 0; j < 8; j++) acc[j] += __shfl_xor(acc[j], m);
  }

  float invden = (cnt > 0) ? 1.f / den : 0.f;

  float v[8];
  v[0] = x0.x + acc[0] * invden;
  v[1] = x0.y + acc[1] * invden;
  v[2] = x0.z + acc[2] * invden;
  v[3] = x0.w + acc[3] * invden;
  v[4] = x1.x + acc[4] * invden;
  v[5] = x1.y + acc[5] * invden;
  v[6] = x1.z + acc[6] * invden;
  v[7] = x1.w + acc[7] * invden;

  // LN partial reduce over heads (flip h bits: 1,2,4); p preserved
  float ps = 0.f;
#pragma unroll
  for (int j = 0; j < 8; j++) ps += v[j];
#pragma unroll
  for (int m = 1; m < 8; m <<= 1) ps += __shfl_xor(ps, m);
  float mean = ps * (1.f / 64.f);
  float pq = 0.f;
#pragma unroll
  for (int j = 0; j < 8; j++) {
    float d = v[j] - mean;
    pq += d * d;
  }
#pragma unroll
  for (int m = 1; m < 8; m <<= 1) pq += __shfl_xor(pq, m);
  float inv = rsqrtf(pq * (1.f / 64.f) + 1e-5f);

  if (e == 0 && nvalid) {
    const float4* gr = (const float4*)(g + h * 8);
    const float4* br = (const float4*)(beta + h * 8);
    float4 ga = gr[0], gb = gr[1];
    float4 ba = br[0], bb = br[1];
    float o[8];
    o[0] = (v[0] - mean) * inv * ga.x + ba.x;
    o[1] = (v[1] - mean) * inv * ga.y + ba.y;
    o[2] = (v[2] - mean) * inv * ga.z + ba.z;
    o[3] = (v[3] - mean) * inv * ga.w + ba.w;
    o[4] = (v[4] - mean) * inv * gb.x + bb.x;
    o[5] = (v[5] - mean) * inv * gb.y + bb.y;
    o[6] = (v[6] - mean) * inv * gb.z + bb.z;
    o[7] = (v[7] - mean) * inv * gb.w + bb.w;
    *(uint4*)(x1b + (size_t)node * 64 + h * 8) =
        make_uint4(f2bf_pk(o[0], o[1]), f2bf_pk(o[2], o[3]),
                   f2bf_pk(o[4], o[5]), f2bf_pk(o[6], o[7]));
  }
}

// ---------------------------------------------------------------------------
extern "C" void kernel_launch(void* const* d_in, const int* in_sizes, int n_in,
                              void* d_out, int out_size, void* d_ws,
                              size_t ws_size, hipStream_t stream) {
  const float* x = (const float*)d_in[0];
  const int* edges = (const int*)d_in[1];
  const float* attn_w = (const float*)d_in[2];
  const float* attn_b = (const float*)d_in[3];
  const float* w1 = (const float*)d_in[4];
  const float* b1 = (const float*)d_in[5];
  const float* w2 = (const float*)d_in[6];
  const float* b2 = (const float*)d_in[7];
  const float* g1 = (const float*)d_in[8];
  const float* bb1 = (const float*)d_in[9];
  const float* g2 = (const float*)d_in[10];
  const float* bb2 = (const float*)d_in[11];

  const int N = in_sizes[0] / 64;
  const int E = in_sizes[1] / 2;
  const int NB = (N + 127) >> BUCKET_SHIFT;
  const int CH = (E + NBLK - 1) / NBLK;
  const int NG = NB * NBLK;

  // ---- workspace layout (bytes) ----
  char* ws = (char*)d_ws;
  size_t oq = 0;                        // qbuf f16  N*64*2
  size_t okv = oq + (size_t)N * 128;    // kv        N*256 (k f16 + v f16)
  size_t ox1b = okv + (size_t)N * 256;  // x1b       N*64*2
  size_t oh = ox1b + (size_t)N * 128;   // h         N*256*2
  size_t oawT = oh + (size_t)N * 512;   // awT  192*64*2
  size_t ow1T = oawT + 192 * 64 * 2;    // w1T  256*64*2
  size_t ow2T = ow1T + 256 * 64 * 2;    // w2T  64*256*2
  size_t oG = ow2T + 64 * 256 * 2;
  size_t oscanG = oG + (size_t)NG * 4;
  size_t oebuf = oscanG + (size_t)NG * 4;
  size_t oecol = oebuf + (size_t)E * 4;
  size_t orowstart = oecol + (size_t)E * 4;
  size_t obsum = orowstart + (size_t)(N + 4) * 4;
  size_t obpre = obsum + 4096;

  unsigned short* qbuf = (unsigned short*)(ws + oq);
  unsigned char* kvb = (unsigned char*)(ws + okv);
  unsigned short* x1b = (unsigned short*)(ws + ox1b);
  unsigned short* hbuf = (unsigned short*)(ws + oh);
  unsigned short* awT = (unsigned short*)(ws + oawT);
  unsigned short* w1T = (unsigned short*)(ws + ow1T);
  unsigned short* w2T = (unsigned short*)(ws + ow2T);
  int* G = (int*)(ws + oG);
  int* scanG = (int*)(ws + oscanG);
  unsigned* ebuf = (unsigned*)(ws + oebuf);
  int* ecol = (int*)(ws + oecol);
  int* rowstart = (int*)(ws + orowstart);
  int* bsum = (int*)(ws + obsum);
  int* bpre = (int*)(ws + obpre);

  // ---- weight converts (independent of partition) ----
  cvt_w2<<<32, 256, 0, stream>>>(attn_w, w1, w2, awT, w1T, w2T);

  // ---- bucket partition + CSR (edge dtype detected per-block) ----
  partition_count<<<NBLK, 256, 0, stream>>>(edges, E, G, NB, CH);
  int nscan = (NG + 1023) / 1024;
  scan_reduce<<<nscan, 1024, 0, stream>>>(G, NG, bsum);
  scan_top<<<1, 1024, 0, stream>>>(bsum, nscan, bpre);
  scan_apply<<<nscan, 1024, 0, stream>>>(G, NG, bpre, scanG);
  partition_scatter<<<NBLK, 256, 0, stream>>>(edges, E, scanG, ebuf, NB, CH);
  bucket_csr<<<NB, 256, 0, stream>>>(ebuf, scanG, ecol, rowstart, N, NB, E);

  const int gblocks = (N + 63) / 64;

  // ---- QKV projection (MFMA, MODE 0, fp32 A converted inline) ----
  mfma_gemm<192, 64, 0><<<gblocks, 256, 0, stream>>>(
      nullptr, x, awT, attn_b, qbuf, kvb, nullptr, nullptr, nullptr, nullptr,
      nullptr, N);

  // ---- attention + LN1 -> x1b (bf16 only); 2 nodes per wave ----
  attn_ln_kernel<<<(N + 7) / 8, 256, 0, stream>>>(x, qbuf, kvb, rowstart, ecol,
                                                  g1, bb1, x1b, N);

  // ---- FFN1 (relu) -> bf16 h (MFMA, MODE 1) ----
  mfma_gemm<256, 64, 1><<<gblocks, 256, 0, stream>>>(
      x1b, nullptr, w1T, b1, nullptr, nullptr, hbuf, nullptr, nullptr, nullptr,
      nullptr, N);

  // ---- FFN2 + bf16 residual + LN2 -> out (MFMA, MODE 2) ----
  mfma_gemm<64, 256, 2><<<gblocks, 256, 0, stream>>>(
      hbuf, nullptr, w2T, b2, nullptr, nullptr, nullptr, x1b, g2, bb2,
      (float*)d_out, N);
}

// Round 7
// 285.680 us; speedup vs baseline: 1.0414x; 1.0414x over previous
//
#include <hip/hip_runtime.h>
#include <hip/hip_bf16.h>

// ---------------------------------------------------------------------------
// Graph transformer layer, fp32 in/out; bf16 MFMA GEMMs; f16 q/k dot via
// v_dot2_f32_f16; f16 v gather with f32 mixed-FMA accumulate (v_fma_mix_f32).
// Pipeline:
//   1. bucket partition (128 rows/bucket, edge dtype detected per-block)
//      -> packed records -> per-bucket counting sort -> CSR
//   2. cvt_w: weights -> bf16 W^T (QKV converts fp32 A fragments inline;
//      attn residual reads fp32 x directly)
//   3. QKV via MFMA: q (pre-scaled log2e/8) -> f16 qbuf[N][64];
//      kv[N][256B]: k f16 [0,128) (h*16) then v f16 [128,256) (h*16)
//   4. attn+LN1 fused: one wave per TWO nodes, lane = e*16 + p*8 + h.
//      ecol segments pre-staged into wave-private LDS (breaks the serialized
//      ec->kv dependency; kv gathers across iterations are independent).
//   5. FFN1 relu via MFMA -> bf16 h ; FFN2 via MFMA + bf16 residual + LN2
// MFMA operand swap: arg0 = W^T frag (LDS), arg1 = X frag (global) so lane
// owns an output row, 4 consecutive cols per acc reg -> vector stores,
// row-LN via shfl_xor(16,32).
// ---------------------------------------------------------------------------

#define WAVE 64
constexpr int BUCKET_SHIFT = 7;
constexpr int NBMAX = 800;

typedef __attribute__((ext_vector_type(8))) short bf16x8;
typedef __attribute__((ext_vector_type(4))) float f32x4;
typedef __attribute__((ext_vector_type(2))) float f32x2;
typedef __attribute__((ext_vector_type(2))) _Float16 h16x2;

__device__ __forceinline__ float bfbits_lo(unsigned u) {
  return __uint_as_float(u << 16);
}
__device__ __forceinline__ float bfbits_hi(unsigned u) {
  return __uint_as_float(u & 0xffff0000u);
}
__device__ __forceinline__ unsigned f2bf_pk(float a, float b) {  // RNE pack
  unsigned ua = __float_as_uint(a);
  unsigned ub = __float_as_uint(b);
  ua = (ua + 0x7fff + ((ua >> 16) & 1)) >> 16;
  ub = (ub + 0x7fff + ((ub >> 16) & 1)) & 0xffff0000u;
  return ua | ub;
}
__device__ __forceinline__ unsigned short f2bf1(float a) {
  unsigned ua = __float_as_uint(a);
  ua = (ua + 0x7fff + ((ua >> 16) & 1)) >> 16;
  return (unsigned short)ua;
}

#if defined(__has_builtin)
#if __has_builtin(__builtin_amdgcn_cvt_pkrtz)
#define HAS_PKRTZ 1
#endif
#if __has_builtin(__builtin_amdgcn_fdot2)
#define HAS_FDOT2 1
#endif
#endif
#define EXP2F(x) exp2f(x)

__device__ __forceinline__ unsigned f2h_pk(float a, float b) {
#ifdef HAS_PKRTZ
  auto h = __builtin_amdgcn_cvt_pkrtz(a, b);  // __fp16 ext_vector(2)
  return __builtin_bit_cast(unsigned, h);
#else
  h16x2 h;
  h.x = (_Float16)a;
  h.y = (_Float16)b;
  return __builtin_bit_cast(unsigned, h);
#endif
}

// 8-wide f16 dot: k row (4x half2) vs q row (4x half2), f32 accumulate
__device__ __forceinline__ float dot8_f16(uint4 kw, uint4 qw) {
#ifdef HAS_FDOT2
  float s = __builtin_amdgcn_fdot2(__builtin_bit_cast(h16x2, kw.x),
                                   __builtin_bit_cast(h16x2, qw.x), 0.f, false);
  s = __builtin_amdgcn_fdot2(__builtin_bit_cast(h16x2, kw.y),
                             __builtin_bit_cast(h16x2, qw.y), s, false);
  s = __builtin_amdgcn_fdot2(__builtin_bit_cast(h16x2, kw.z),
                             __builtin_bit_cast(h16x2, qw.z), s, false);
  s = __builtin_amdgcn_fdot2(__builtin_bit_cast(h16x2, kw.w),
                             __builtin_bit_cast(h16x2, qw.w), s, false);
  return s;
#else
  unsigned kk[4] = {kw.x, kw.y, kw.z, kw.w};
  unsigned qq[4] = {qw.x, qw.y, qw.z, qw.w};
  float s = 0.f;
#pragma unroll
  for (int i = 0; i < 4; i++) {
    h16x2 a = __builtin_bit_cast(h16x2, kk[i]);
    h16x2 b = __builtin_bit_cast(h16x2, qq[i]);
    s += (float)a.x * (float)b.x + (float)a.y * (float)b.y;
  }
  return s;
#endif
}

// 8 f16 v-elems (uint4) * e -> f32 accumulate; pattern-matches v_fma_mix_f32
__device__ __forceinline__ void accmix8(uint4 w, float e, float acc[8]) {
  h16x2 p;
  p = __builtin_bit_cast(h16x2, w.x);
  acc[0] += (float)p.x * e;
  acc[1] += (float)p.y * e;
  p = __builtin_bit_cast(h16x2, w.y);
  acc[2] += (float)p.x * e;
  acc[3] += (float)p.y * e;
  p = __builtin_bit_cast(h16x2, w.z);
  acc[4] += (float)p.x * e;
  acc[5] += (float)p.y * e;
  p = __builtin_bit_cast(h16x2, w.w);
  acc[6] += (float)p.x * e;
  acc[7] += (float)p.y * e;
}

// ------------------------- weight converts ---------------------------------
__global__ __launch_bounds__(256) void cvt_w2(
    const float* __restrict__ aw, const float* __restrict__ w1,
    const float* __restrict__ w2, unsigned short* __restrict__ awT,
    unsigned short* __restrict__ w1T, unsigned short* __restrict__ w2T) {
  int tid = blockIdx.x * 256 + threadIdx.x;
  int stride = gridDim.x * 256;
  for (int i = tid; i < 192 * 64; i += stride) {
    int nn = i >> 6, kk = i & 63;
    awT[i] = f2bf1(aw[kk * 192 + nn]);
  }
  for (int i = tid; i < 256 * 64; i += stride) {
    int nn = i >> 6, kk = i & 63;
    w1T[i] = f2bf1(w1[kk * 256 + nn]);
  }
  for (int i = tid; i < 64 * 256; i += stride) {
    int nn = i >> 8, kk = i & 255;
    w2T[i] = f2bf1(w2[kk * 64 + nn]);
  }
}

// ------------------------- MFMA GEMM ---------------------------------------
// 128 rows/block, 4 waves x 2x16 rows.
// MODE 0: QKV split, A is fp32 (converted inline):
//         q*(log2e/8) -> f16 out_q[N][64]; k -> f16 kv[0,128); v -> f16 [128,256)
// MODE 1: relu + bf16 store -> out_h
// MODE 2: + bias + bf16 resid, LayerNorm over 64 cols -> out_f fp32
template <int NCOLS, int K, int MODE>
__global__ __launch_bounds__(256) void mfma_gemm(
    const unsigned short* __restrict__ A, const float* __restrict__ Af,
    const unsigned short* __restrict__ BT, const float* __restrict__ bias,
    unsigned short* __restrict__ out_q, unsigned char* __restrict__ out_kv,
    unsigned short* __restrict__ out_h,
    const unsigned short* __restrict__ resid, const float* __restrict__ g,
    const float* __restrict__ beta, float* __restrict__ out_f, int n) {
  constexpr int KP = K + 8;  // +16B pad -> only free 2-way bank alias
  constexpr int NT = NCOLS / 16;
  constexpr int NKC = K / 32;
  __shared__ unsigned short sB[NCOLS * KP];

  const int tid = threadIdx.x;
  {
    const uint4* src = (const uint4*)BT;
    for (int idx = tid; idx < NCOLS * K / 8; idx += 256) {
      int nn = idx / (K / 8), kq = idx % (K / 8);
      *(uint4*)&sB[nn * KP + kq * 8] = src[idx];
    }
  }
  __syncthreads();

  const int wid = tid >> 6, lane = tid & 63;
  const int l15 = lane & 15, quad = lane >> 4;
  const int rowbase = blockIdx.x * 128 + wid * 32;

  bf16x8 afrag[2][NKC];
#pragma unroll
  for (int rg = 0; rg < 2; rg++) {
    int row = rowbase + rg * 16 + l15;
    if (row >= n) row = n - 1;
    if constexpr (MODE == 0) {
      const float4* ap = (const float4*)(Af + (size_t)row * K);
#pragma unroll
      for (int kc = 0; kc < NKC; kc++) {
        float4 a = ap[kc * 8 + quad * 2], b = ap[kc * 8 + quad * 2 + 1];
        union {
          unsigned u[4];
          bf16x8 v;
        } z;
        z.u[0] = f2bf_pk(a.x, a.y);
        z.u[1] = f2bf_pk(a.z, a.w);
        z.u[2] = f2bf_pk(b.x, b.y);
        z.u[3] = f2bf_pk(b.z, b.w);
        afrag[rg][kc] = z.v;
      }
    } else {
      const bf16x8* ap = (const bf16x8*)(A + (size_t)row * K);
#pragma unroll
      for (int kc = 0; kc < NKC; kc++) afrag[rg][kc] = ap[kc * 4 + quad];
    }
  }

  f32x4 acc[2][NT];
#pragma unroll
  for (int rg = 0; rg < 2; rg++)
#pragma unroll
    for (int t = 0; t < NT; t++) acc[rg][t] = (f32x4){0.f, 0.f, 0.f, 0.f};

#pragma unroll
  for (int t = 0; t < NT; t++) {
#pragma unroll
    for (int kc = 0; kc < NKC; kc++) {
      bf16x8 b = *(const bf16x8*)&sB[(t * 16 + l15) * KP + kc * 32 + quad * 8];
      acc[0][t] = __builtin_amdgcn_mfma_f32_16x16x32_bf16(b, afrag[0][kc],
                                                          acc[0][t], 0, 0, 0);
      acc[1][t] = __builtin_amdgcn_mfma_f32_16x16x32_bf16(b, afrag[1][kc],
                                                          acc[1][t], 0, 0, 0);
    }
  }

  if (MODE == 0) {
    constexpr float QSCALE = 0.125f * 1.44269504088896f;  // log2e/8
#pragma unroll
    for (int rg = 0; rg < 2; rg++) {
      int row = rowbase + rg * 16 + l15;
      if (row >= n) continue;
#pragma unroll
      for (int t = 0; t < NT; t++) {
        int c0 = t * 16 + quad * 4;
        float4 bb = *(const float4*)&bias[c0];
        float v0 = acc[rg][t].x + bb.x, v1 = acc[rg][t].y + bb.y;
        float v2 = acc[rg][t].z + bb.z, v3 = acc[rg][t].w + bb.w;
        int hh = c0 / 24, rem = c0 % 24;  // 4-col group stays in one section
        if (rem < 8) {
          v0 *= QSCALE;
          v1 *= QSCALE;
          v2 *= QSCALE;
          v3 *= QSCALE;
          *(uint2*)(out_q + (size_t)row * 64 + hh * 8 + rem) =
              make_uint2(f2h_pk(v0, v1), f2h_pk(v2, v3));  // q f16 (log2 dom)
        } else if (rem < 16) {
          *(uint2*)(out_kv + ((size_t)row << 8) + hh * 16 + (rem - 8) * 2) =
              make_uint2(f2h_pk(v0, v1), f2h_pk(v2, v3));  // k f16 [0,128)
        } else {
          *(uint2*)(out_kv + ((size_t)row << 8) + 128 + hh * 16 +
                    (rem - 16) * 2) =
              make_uint2(f2h_pk(v0, v1), f2h_pk(v2, v3));  // v f16 [128,256)
        }
      }
    }
  } else if (MODE == 1) {
#pragma unroll
    for (int rg = 0; rg < 2; rg++) {
      int row = rowbase + rg * 16 + l15;
      if (row >= n) continue;
#pragma unroll
      for (int t = 0; t < NT; t++) {
        int c0 = t * 16 + quad * 4;
        float4 bb = *(const float4*)&bias[c0];
        float v0 = fmaxf(acc[rg][t].x + bb.x, 0.f);
        float v1 = fmaxf(acc[rg][t].y + bb.y, 0.f);
        float v2 = fmaxf(acc[rg][t].z + bb.z, 0.f);
        float v3 = fmaxf(acc[rg][t].w + bb.w, 0.f);
        *(uint2*)(out_h + (size_t)row * NCOLS + c0) =
            make_uint2(f2bf_pk(v0, v1), f2bf_pk(v2, v3));
      }
    }
  } else {
#pragma unroll
    for (int rg = 0; rg < 2; rg++) {
      int row = rowbase + rg * 16 + l15;
      bool ok = row < n;
      int rowc = ok ? row : n - 1;
      float vals[4][4];
      float ps = 0.f, pq = 0.f;
#pragma unroll
      for (int t = 0; t < 4; t++) {
        int c0 = t * 16 + quad * 4;
        float4 bb = *(const float4*)&bias[c0];
        uint2 rr = *(const uint2*)&resid[(size_t)rowc * 64 + c0];
        vals[t][0] = acc[rg][t].x + bb.x + bfbits_lo(rr.x);
        vals[t][1] = acc[rg][t].y + bb.y + bfbits_hi(rr.x);
        vals[t][2] = acc[rg][t].z + bb.z + bfbits_lo(rr.y);
        vals[t][3] = acc[rg][t].w + bb.w + bfbits_hi(rr.y);
#pragma unroll
        for (int r = 0; r < 4; r++) {
          ps += vals[t][r];
          pq += vals[t][r] * vals[t][r];
        }
      }
      ps += __shfl_xor(ps, 16);
      ps += __shfl_xor(ps, 32);
      pq += __shfl_xor(pq, 16);
      pq += __shfl_xor(pq, 32);
      float mean = ps * (1.f / 64.f);
      float var = pq * (1.f / 64.f) - mean * mean;
      float inv = rsqrtf(var + 1e-5f);
      if (ok) {
#pragma unroll
        for (int t = 0; t < 4; t++) {
          int c0 = t * 16 + quad * 4;
          float4 gg = *(const float4*)&g[c0];
          float4 be = *(const float4*)&beta[c0];
          float4 o = make_float4((vals[t][0] - mean) * inv * gg.x + be.x,
                                 (vals[t][1] - mean) * inv * gg.y + be.y,
                                 (vals[t][2] - mean) * inv * gg.z + be.z,
                                 (vals[t][3] - mean) * inv * gg.w + be.w);
          *(float4*)&out_f[(size_t)row * 64 + c0] = o;
        }
      }
    }
  }
}

// ------------------------- edge helpers ------------------------------------
__device__ __forceinline__ int edge_row(const int* e, int i, bool is64) {
  return is64 ? e[2 * (size_t)i] : e[i];
}
__device__ __forceinline__ int edge_col(const int* e, int i, int E, bool is64) {
  return is64 ? e[2 * ((size_t)E + i)] : e[(size_t)E + i];
}

// ------------------------- bucket partition --------------------------------
// Edge dtype (int64 vs int32) detected per-block: sample the first 2048
// odd-index words; int64 high words are all 0, int32 edge data is not.
__global__ __launch_bounds__(256) void partition_count(
    const int* __restrict__ e, int E, int* __restrict__ G, int NB, int CH) {
  __shared__ int h[NBMAX];
  __shared__ int s32;
  if (threadIdx.x == 0) s32 = 0;
  for (int b = threadIdx.x; b < NB; b += 256) h[b] = 0;
  __syncthreads();
  unsigned v = 0;
  for (int i = threadIdx.x; i < 2048; i += 256) v |= (unsigned)e[2 * i + 1];
  if (v) s32 = 1;
  __syncthreads();
  bool is64 = (s32 == 0);
  int c0 = blockIdx.x * CH, c1 = min(E, c0 + CH);
  for (int i = c0 + threadIdx.x; i < c1; i += 256)
    atomicAdd(&h[edge_row(e, i, is64) >> BUCKET_SHIFT], 1);
  __syncthreads();
  for (int b = threadIdx.x; b < NB; b += 256) G[b * 256 + blockIdx.x] = h[b];
}

__global__ __launch_bounds__(1024) void scan_reduce(const int* __restrict__ in,
                                                    int n,
                                                    int* __restrict__ bsum) {
  __shared__ int sdata[16];
  int tid = threadIdx.x;
  int idx = blockIdx.x * 1024 + tid;
  int v = (idx < n) ? in[idx] : 0;
#pragma unroll
  for (int m = 1; m < WAVE; m <<= 1) v += __shfl_xor(v, m);
  if ((tid & 63) == 0) sdata[tid >> 6] = v;
  __syncthreads();
  if (tid < 16) {
    int s = sdata[tid];
#pragma unroll
    for (int m = 1; m < 16; m <<= 1) s += __shfl_xor(s, m);
    if (tid == 0) bsum[blockIdx.x] = s;
  }
}

__global__ __launch_bounds__(256) void scan_top(const int* __restrict__ bsum,
                                                int nb,
                                                int* __restrict__ bpre) {
  __shared__ int wsum[4];
  int tid = threadIdx.x;
  int lane = tid & 63, wid = tid >> 6;
  int v = (tid < nb) ? bsum[tid] : 0;
  int incl = v;
#pragma unroll
  for (int m = 1; m < WAVE; m <<= 1) {
    int t = __shfl_up(incl, m);
    if (lane >= m) incl += t;
  }
  if (lane == 63) wsum[wid] = incl;
  __syncthreads();
  int add = 0;
  for (int w = 0; w < wid; w++) add += wsum[w];
  if (tid < nb) bpre[tid] = add + incl - v;
}

__global__ __launch_bounds__(1024) void scan_apply(
    const int* __restrict__ in, int n, const int* __restrict__ bpre,
    int* __restrict__ outscan) {
  __shared__ int wtot[16];
  __shared__ int wexcl[16];
  int tid = threadIdx.x;
  int idx = blockIdx.x * 1024 + tid;
  int v = (idx < n) ? in[idx] : 0;
  int incl = v;
#pragma unroll
  for (int m = 1; m < WAVE; m <<= 1) {
    int t = __shfl_up(incl, m);
    if ((tid & 63) >= m) incl += t;
  }
  int wid = tid >> 6;
  if ((tid & 63) == 63) wtot[wid] = incl;
  __syncthreads();
  if (tid < 16) {
    int w = wtot[tid];
    int wi = w;
#pragma unroll
    for (int m = 1; m < 16; m <<= 1) {
      int t = __shfl_up(wi, m);
      if (tid >= m) wi += t;
    }
    wexcl[tid] = wi - w;
  }
  __syncthreads();
  if (idx < n) outscan[idx] = bpre[blockIdx.x] + wexcl[wid] + incl - v;
}

__global__ __launch_bounds__(256) void partition_scatter(
    const int* __restrict__ e, int E, const int* __restrict__ scanG,
    unsigned* __restrict__ ebuf, int NB, int CH) {
  __shared__ int base[NBMAX];
  __shared__ int s32;
  if (threadIdx.x == 0) s32 = 0;
  for (int b = threadIdx.x; b < NB; b += 256)
    base[b] = scanG[b * 256 + blockIdx.x];
  __syncthreads();
  unsigned v = 0;
  for (int i = threadIdx.x; i < 2048; i += 256) v |= (unsigned)e[2 * i + 1];
  if (v) s32 = 1;
  __syncthreads();
  bool is64 = (s32 == 0);
  int c0 = blockIdx.x * CH, c1 = min(E, c0 + CH);
  for (int i = c0 + threadIdx.x; i < c1; i += 256) {
    int r = edge_row(e, i, is64);
    int c = edge_col(e, i, E, is64);
    int pos = atomicAdd(&base[r >> BUCKET_SHIFT], 1);
    ebuf[pos] = ((unsigned)(r & 127) << 17) | (unsigned)c;
  }
}

__global__ __launch_bounds__(256) void bucket_csr(
    const unsigned* __restrict__ ebuf, const int* __restrict__ scanG,
    int* __restrict__ ecol, int* __restrict__ rowstart, int n, int NB, int E) {
  __shared__ int cnt[128], offs[128], cur[128];
  const int b = blockIdx.x;
  const int tid = threadIdx.x;
  const int start = scanG[b * 256];
  const int end = (b + 1 < NB) ? scanG[(b + 1) * 256] : E;
  if (tid < 128) cnt[tid] = 0;
  __syncthreads();
  for (int i = start + tid; i < end; i += 256)
    atomicAdd(&cnt[(ebuf[i] >> 17) & 127], 1);
  __syncthreads();
  if (tid < 128) offs[tid] = cnt[tid];
  __syncthreads();
  for (int s = 1; s < 128; s <<= 1) {
    int t = 0;
    if (tid < 128 && tid >= s) t = offs[tid - s];
    __syncthreads();
    if (tid < 128) offs[tid] += t;
    __syncthreads();
  }
  if (tid < 128) {
    int excl = offs[tid] - cnt[tid];
    cur[tid] = start + excl;
    int gr = (b << BUCKET_SHIFT) + tid;
    if (gr < n) rowstart[gr] = start + excl;
  }
  if (b == NB - 1 && tid == 0) rowstart[n] = E;
  __syncthreads();
  for (int i = start + tid; i < end; i += 256) {
    unsigned p = ebuf[i];
    int pos = atomicAdd(&cur[(p >> 17) & 127], 1);
    ecol[pos] = (int)(p & 0x1FFFF);
  }
}

// ------------------------- fused attention + LN1 ---------------------------
// One wave per TWO nodes; lane = e*16 + p*8 + h (e=edge-slot 0..3, p=node
// parity, h=head). kv per node (256B): [0,128) k f16 (h*16), [128,256) v f16.
// q pre-scaled by log2e/8 (f16, log2 domain). Residual from fp32 x.
// ecol segments staged into wave-private LDS (first 128 edges/node; rare
// global tail loop beyond) so in-loop index reads are low-latency and kv
// gathers across iterations are independent (memory-parallel).
__global__ __launch_bounds__(256) void attn_ln_kernel(
    const float* __restrict__ x, const unsigned short* __restrict__ qbuf,
    const unsigned char* __restrict__ kv, const int* __restrict__ rowstart,
    const int* __restrict__ ecol, const float* __restrict__ g,
    const float* __restrict__ beta, unsigned short* __restrict__ x1b, int n) {
  __shared__ int ecs[4][2][128];  // 4 KB, wave-private slices
  int wave = threadIdx.x >> 6;
  int lane = threadIdx.x & 63;
  int node0 = (blockIdx.x * 4 + wave) * 2;
  if (node0 >= n) return;
  const int e = lane >> 4;        // 0..3 edge slot
  const int h = lane & 7;         // head
  const int p = (lane >> 3) & 1;  // node parity
  int node = node0 + p;
  bool nvalid = node < n;
  int nodec = nvalid ? node : n - 1;

  uint4 qp = ((const uint4*)qbuf)[(size_t)nodec * 8 + h];  // 8 f16, log2 dom

  // residual load hoisted above the edge loop
  const float* xr = x + (size_t)nodec * 64 + h * 8;
  float4 x0 = *(const float4*)xr;
  float4 x1 = *(const float4*)(xr + 4);

  int start = rowstart[nodec];
  int cnt = nvalid ? rowstart[nodec + 1] - start : 0;
  const int* ec = ecol + start;
  const int koff = h * 16, voff = 128 + h * 16;

  // ---- stage both nodes' ecol segments into LDS (coalesced, wave-wide) ----
  int s0 = __shfl(start, 0), c0n = __shfl(cnt, 0);  // lane 0: p=0
  int s1 = __shfl(start, 8), c1n = __shfl(cnt, 8);  // lane 8: p=1
  int c0c = min(c0n, 128), c1c = min(c1n, 128);
  for (int i = lane; i < c0c; i += 64) ecs[wave][0][i] = ecol[s0 + i];
  for (int i = lane; i < c1c; i += 64) ecs[wave][1][i] = ecol[s1 + i];
  // LDS ops are in-order per wave: reads below see these writes (no barrier).

  int cntc = min(cnt, 128);

  float den = 0.f;
  float acc[8] = {0.f, 0.f, 0.f, 0.f, 0.f, 0.f, 0.f, 0.f};

  int iters = (cntc + 3) >> 2;
  int maxit = max(iters, __shfl_xor(iters, 8));  // pair with p^1 lane

  int it = 0;
  for (; it + 2 <= maxit; it += 2) {
    int i0 = it * 4 + e;
    int i1 = i0 + 4;
    bool b0 = i0 < cntc;
    bool b1 = i1 < cntc;
    int c0 = b0 ? ecs[wave][p][i0] : 0;
    int c1 = b1 ? ecs[wave][p][i1] : 0;
    const unsigned char* r0 = kv + ((size_t)c0 << 8);
    const unsigned char* r1 = kv + ((size_t)c1 << 8);
    uint4 kw0 = *(const uint4*)(r0 + koff);
    uint4 vw0 = *(const uint4*)(r0 + voff);
    uint4 kw1 = *(const uint4*)(r1 + koff);
    uint4 vw1 = *(const uint4*)(r1 + voff);
    float a0 = dot8_f16(kw0, qp);
    float a1 = dot8_f16(kw1, qp);
    float e0 = b0 ? EXP2F(a0) : 0.f;
    float e1 = b1 ? EXP2F(a1) : 0.f;
    den += e0 + e1;
    accmix8(vw0, e0, acc);
    accmix8(vw1, e1, acc);
  }
  if (it < maxit) {
    int i0 = it * 4 + e;
    bool b0 = i0 < cntc;
    int c0 = b0 ? ecs[wave][p][i0] : 0;
    const unsigned char* r0 = kv + ((size_t)c0 << 8);
    uint4 kw0 = *(const uint4*)(r0 + koff);
    uint4 vw0 = *(const uint4*)(r0 + voff);
    float a0 = dot8_f16(kw0, qp);
    float e0 = b0 ? EXP2F(a0) : 0.f;
    den += e0;
    accmix8(vw0, e0, acc);
  }

  // rare tail: edges beyond the 128-entry LDS window (any-degree correctness)
  for (int i = 128 + e; i < cnt; i += 4) {
    int c = ec[i];
    const unsigned char* r = kv + ((size_t)c << 8);
    uint4 kw = *(const uint4*)(r + koff);
    uint4 vw = *(const uint4*)(r + voff);
    float a = dot8_f16(kw, qp);
    float ee = EXP2F(a);
    den += ee;
    accmix8(vw, ee, acc);
  }

  // reduce over the 4 edge-slots (flip e bits: 16, 32); p and h preserved
#pragma unroll
  for (int m = 16; m < 64; m <<= 1) {
    den += __shfl_xor(den, m);
#pragma unroll
    for (int j = 0; j < 8; j++) acc[j] += __shfl_xor(acc[j], m);
  }

  float invden = (cnt > 0) ? 1.f / den : 0.f;

  float v[8];
  v[0] = x0.x + acc[0] * invden;
  v[1] = x0.y + acc[1] * invden;
  v[2] = x0.z + acc[2] * invden;
  v[3] = x0.w + acc[3] * invden;
  v[4] = x1.x + acc[4] * invden;
  v[5] = x1.y + acc[5] * invden;
  v[6] = x1.z + acc[6] * invden;
  v[7] = x1.w + acc[7] * invden;

  // LN partial reduce over heads (flip h bits: 1,2,4); p preserved
  float ps = 0.f;
#pragma unroll
  for (int j = 0; j < 8; j++) ps += v[j];
#pragma unroll
  for (int m = 1; m < 8; m <<= 1) ps += __shfl_xor(ps, m);
  float mean = ps * (1.f / 64.f);
  float pq = 0.f;
#pragma unroll
  for (int j = 0; j < 8; j++) {
    float d = v[j] - mean;
    pq += d * d;
  }
#pragma unroll
  for (int m = 1; m < 8; m <<= 1) pq += __shfl_xor(pq, m);
  float inv = rsqrtf(pq * (1.f / 64.f) + 1e-5f);

  if (e == 0 && nvalid) {
    const float4* gr = (const float4*)(g + h * 8);
    const float4* br = (const float4*)(beta + h * 8);
    float4 ga = gr[0], gb = gr[1];
    float4 ba = br[0], bb = br[1];
    float o[8];
    o[0] = (v[0] - mean) * inv * ga.x + ba.x;
    o[1] = (v[1] - mean) * inv * ga.y + ba.y;
    o[2] = (v[2] - mean) * inv * ga.z + ba.z;
    o[3] = (v[3] - mean) * inv * ga.w + ba.w;
    o[4] = (v[4] - mean) * inv * gb.x + bb.x;
    o[5] = (v[5] - mean) * inv * gb.y + bb.y;
    o[6] = (v[6] - mean) * inv * gb.z + bb.z;
    o[7] = (v[7] - mean) * inv * gb.w + bb.w;
    *(uint4*)(x1b + (size_t)node * 64 + h * 8) =
        make_uint4(f2bf_pk(o[0], o[1]), f2bf_pk(o[2], o[3]),
                   f2bf_pk(o[4], o[5]), f2bf_pk(o[6], o[7]));
  }
}

// ---------------------------------------------------------------------------
extern "C" void kernel_launch(void* const* d_in, const int* in_sizes, int n_in,
                              void* d_out, int out_size, void* d_ws,
                              size_t ws_size, hipStream_t stream) {
  const float* x = (const float*)d_in[0];
  const int* edges = (const int*)d_in[1];
  const float* attn_w = (const float*)d_in[2];
  const float* attn_b = (const float*)d_in[3];
  const float* w1 = (const float*)d_in[4];
  const float* b1 = (const float*)d_in[5];
  const float* w2 = (const float*)d_in[6];
  const float* b2 = (const float*)d_in[7];
  const float* g1 = (const float*)d_in[8];
  const float* bb1 = (const float*)d_in[9];
  const float* g2 = (const float*)d_in[10];
  const float* bb2 = (const float*)d_in[11];

  const int N = in_sizes[0] / 64;
  const int E = in_sizes[1] / 2;
  const int NB = (N + 127) >> BUCKET_SHIFT;
  const int CH = (E + 255) / 256;
  const int NG = NB * 256;

  // ---- workspace layout (bytes) ----
  char* ws = (char*)d_ws;
  size_t oq = 0;                        // qbuf f16  N*64*2
  size_t okv = oq + (size_t)N * 128;    // kv        N*256 (k f16 + v f16)
  size_t ox1b = okv + (size_t)N * 256;  // x1b       N*64*2
  size_t oh = ox1b + (size_t)N * 128;   // h         N*256*2
  size_t oawT = oh + (size_t)N * 512;   // awT  192*64*2
  size_t ow1T = oawT + 192 * 64 * 2;    // w1T  256*64*2
  size_t ow2T = ow1T + 256 * 64 * 2;    // w2T  64*256*2
  size_t oG = ow2T + 64 * 256 * 2;
  size_t oscanG = oG + (size_t)NG * 4;
  size_t oebuf = oscanG + (size_t)NG * 4;
  size_t oecol = oebuf + (size_t)E * 4;
  size_t orowstart = oecol + (size_t)E * 4;
  size_t obsum = orowstart + (size_t)(N + 4) * 4;
  size_t obpre = obsum + 1024;

  unsigned short* qbuf = (unsigned short*)(ws + oq);
  unsigned char* kvb = (unsigned char*)(ws + okv);
  unsigned short* x1b = (unsigned short*)(ws + ox1b);
  unsigned short* hbuf = (unsigned short*)(ws + oh);
  unsigned short* awT = (unsigned short*)(ws + oawT);
  unsigned short* w1T = (unsigned short*)(ws + ow1T);
  unsigned short* w2T = (unsigned short*)(ws + ow2T);
  int* G = (int*)(ws + oG);
  int* scanG = (int*)(ws + oscanG);
  unsigned* ebuf = (unsigned*)(ws + oebuf);
  int* ecol = (int*)(ws + oecol);
  int* rowstart = (int*)(ws + orowstart);
  int* bsum = (int*)(ws + obsum);
  int* bpre = (int*)(ws + obpre);

  // ---- weight converts (independent of partition) ----
  cvt_w2<<<32, 256, 0, stream>>>(attn_w, w1, w2, awT, w1T, w2T);

  // ---- bucket partition + CSR (edge dtype detected per-block) ----
  partition_count<<<256, 256, 0, stream>>>(edges, E, G, NB, CH);
  int nscan = (NG + 1023) / 1024;
  scan_reduce<<<nscan, 1024, 0, stream>>>(G, NG, bsum);
  scan_top<<<1, 256, 0, stream>>>(bsum, nscan, bpre);
  scan_apply<<<nscan, 1024, 0, stream>>>(G, NG, bpre, scanG);
  partition_scatter<<<256, 256, 0, stream>>>(edges, E, scanG, ebuf, NB, CH);
  bucket_csr<<<NB, 256, 0, stream>>>(ebuf, scanG, ecol, rowstart, N, NB, E);

  const int gblocks = (N + 127) / 128;

  // ---- QKV projection (MFMA, MODE 0, fp32 A converted inline) ----
  mfma_gemm<192, 64, 0><<<gblocks, 256, 0, stream>>>(
      nullptr, x, awT, attn_b, qbuf, kvb, nullptr, nullptr, nullptr, nullptr,
      nullptr, N);

  // ---- attention + LN1 -> x1b (bf16 only); 2 nodes per wave ----
  attn_ln_kernel<<<(N + 7) / 8, 256, 0, stream>>>(x, qbuf, kvb, rowstart, ecol,
                                                  g1, bb1, x1b, N);

  // ---- FFN1 (relu) -> bf16 h (MFMA, MODE 1) ----
  mfma_gemm<256, 64, 1><<<gblocks, 256, 0, stream>>>(
      x1b, nullptr, w1T, b1, nullptr, nullptr, hbuf, nullptr, nullptr, nullptr,
      nullptr, N);

  // ---- FFN2 + bf16 residual + LN2 -> out (MFMA, MODE 2) ----
  mfma_gemm<64, 256, 2><<<gblocks, 256, 0, stream>>>(
      hbuf, nullptr, w2T, b2, nullptr, nullptr, nullptr, x1b, g2, bb2,
      (float*)d_out, N);
}